// Round 5
// baseline (40224.576 us; speedup 1.0000x reference)
//
#include <hip/hip_runtime.h>

#define SEQ 8192
#define H 1024

// ---------------------------------------------------------------------------
// Projection GEMM (NT): C[i][j] = bias[j] + sum_k A[i][k]*B[j][k]
// (unchanged — ~0.6 ms, not the bottleneck)
// ---------------------------------------------------------------------------
#define KC 32
#define LDT 68

__global__ __launch_bounds__(256) void proj_gemm(
    const float* __restrict__ A,
    const float* __restrict__ B0, const float* __restrict__ b0, float* __restrict__ C0,
    const float* __restrict__ B1, const float* __restrict__ b1, float* __restrict__ C1,
    const float* __restrict__ B2, const float* __restrict__ b2, float* __restrict__ C2)
{
    __shared__ __align__(16) float As[KC * LDT];
    __shared__ __align__(16) float Bs[KC * LDT];

    const float* Bm; const float* bias; float* C;
    if (blockIdx.z == 0)      { Bm = B0; bias = b0; C = C0; }
    else if (blockIdx.z == 1) { Bm = B1; bias = b1; C = C1; }
    else                      { Bm = B2; bias = b2; C = C2; }

    const int j0 = blockIdx.x * 64;
    const int i0 = blockIdx.y * 64;
    const int tid = threadIdx.x;
    const int tx = tid & 15, ty = tid >> 4;
    const int lrow = tid >> 3;
    const int lkq  = tid & 7;

    float acc[4][4];
#pragma unroll
    for (int r = 0; r < 4; r++)
#pragma unroll
        for (int c = 0; c < 4; c++) acc[r][c] = 0.f;

    for (int k0 = 0; k0 < H; k0 += KC) {
#pragma unroll
        for (int half = 0; half < 2; half++) {
            const int row = lrow + half * 32;
            float4 a = *(const float4*)&A[(size_t)(i0 + row) * H + k0 + 4 * lkq];
            As[(4 * lkq + 0) * LDT + row] = a.x;
            As[(4 * lkq + 1) * LDT + row] = a.y;
            As[(4 * lkq + 2) * LDT + row] = a.z;
            As[(4 * lkq + 3) * LDT + row] = a.w;
            float4 b = *(const float4*)&Bm[(size_t)(j0 + row) * H + k0 + 4 * lkq];
            Bs[(4 * lkq + 0) * LDT + row] = b.x;
            Bs[(4 * lkq + 1) * LDT + row] = b.y;
            Bs[(4 * lkq + 2) * LDT + row] = b.z;
            Bs[(4 * lkq + 3) * LDT + row] = b.w;
        }
        __syncthreads();
#pragma unroll
        for (int k = 0; k < KC; k++) {
            float4 a4 = *(const float4*)&As[k * LDT + ty * 4];
            float4 b4 = *(const float4*)&Bs[k * LDT + tx * 4];
            acc[0][0] += a4.x * b4.x; acc[0][1] += a4.x * b4.y;
            acc[0][2] += a4.x * b4.z; acc[0][3] += a4.x * b4.w;
            acc[1][0] += a4.y * b4.x; acc[1][1] += a4.y * b4.y;
            acc[1][2] += a4.y * b4.z; acc[1][3] += a4.y * b4.w;
            acc[2][0] += a4.z * b4.x; acc[2][1] += a4.z * b4.y;
            acc[2][2] += a4.z * b4.z; acc[2][3] += a4.z * b4.w;
            acc[3][0] += a4.w * b4.x; acc[3][1] += a4.w * b4.y;
            acc[3][2] += a4.w * b4.z; acc[3][3] += a4.w * b4.w;
        }
        __syncthreads();
    }

    float4 bi = *(const float4*)&bias[j0 + tx * 4];
#pragma unroll
    for (int r = 0; r < 4; r++) {
        float4 o;
        o.x = acc[r][0] + bi.x; o.y = acc[r][1] + bi.y;
        o.z = acc[r][2] + bi.z; o.w = acc[r][3] + bi.w;
        *(float4*)&C[(size_t)(i0 + ty * 4 + r) * H + j0 + tx * 4] = o;
    }
}

// ---------------------------------------------------------------------------
// GRU scan v5: XCD-pinned cohort — communication through one XCD's L2.
//   - 32 blocks x 512 threads, all on XCD 0. Blocks read HW_REG_XCC_ID and
//     claim one of 32 slots (atomicAdd); everyone else exits. Launch 768
//     blocks so freed CUs get backfilled until 32 XCD0 blocks have claimed.
//   - Each wave owns 4 units; weights register-resident (192 VGPR) and
//     PINNED via asm so the compiler cannot re-load them per step (12 MB of
//     weights do NOT fit one XCD's 4 MB L2 — re-reading would be fatal).
//   - Publish: dual-store each tagged (value, tag) packet: plain store to
//     thL (lands in XCD0's L2, write-back; CDNA L1 is write-through so the
//     store is L2-visible) + agent store to thR (MALL).
//   - Poll: inline-asm `global_load_dwordx2 ... sc0` (bypass own L1, hit the
//     SHARED XCD L2 — ~200cy RT instead of ~MALL/HBM ~1000cy). Every 8th
//     failed try, check the agent copy: if dispatch ever scatters the
//     cohort, we degrade to MALL polling instead of deadlocking.
//   - Ring of 8 step-slots, monotone tags: no init, replay-safe (leftover
//     tags can only collide at the final step, where the stale packet is the
//     previous run's bit-identical value; 0xAA poison never matches).
//   - hs double-buffered -> ONE barrier per step. x-projections loaded
//     AFTER the barrier (the compiler's pre-barrier vmcnt(0) drain would
//     otherwise serialize their HBM miss into the critical path); their
//     ~900cy latency hides under the FMA phase.
// ---------------------------------------------------------------------------
#define RING   8
#define COHORT 32            // blocks in cohort (all on XCD 0)
#define WAVES  8             // waves per block (512 threads)
#define UPW    4             // units per wave
#define UPB    (WAVES * UPW) // 32 units per block

__device__ __forceinline__ float gatef(float ax_u, float ax_r, float ax_c,
                                       float su, float sr, float sw, float hp) {
    float u    = 1.f / (1.f + __expf(-(ax_u + su)));
    float r    = 1.f / (1.f + __expf(-(ax_r + sr)));
    float cand = 1.f / (1.f + __expf(-(ax_c + r * sw)));
    return u * hp + (1.f - u) * cand;
}

__global__ void zero_claim(int* c) { if (threadIdx.x == 0) *c = 0; }

__global__ __launch_bounds__(512, 2) void gru_scan(
    const float* __restrict__ xu, const float* __restrict__ xr, const float* __restrict__ xc,
    const float* __restrict__ Wu, const float* __restrict__ Wr, const float* __restrict__ W,
    unsigned long long* __restrict__ thL,  // local ring  (XCD0 L2, plain/sc0)
    unsigned long long* __restrict__ thR,  // remote ring (agent scope, fallback)
    int* __restrict__ claim,
    float* __restrict__ out)               // d_out: [H h_final][SEQ*H outputs]
{
    __shared__ __align__(16) float hs[2][H];
    __shared__ int slot_s;

    unsigned int xcc;
    asm volatile("s_getreg_b32 %0, hwreg(HW_REG_XCC_ID)" : "=s"(xcc));
    if (xcc != 0) return;                       // wrong chiplet: free the CU

    if (threadIdx.x == 0) slot_s = atomicAdd(claim, 1);
    __syncthreads();
    const int slot = slot_s;
    if (slot >= COHORT) return;                 // cohort full: free the CU

    const int tid  = threadIdx.x;               // 0..511
    const int wid  = tid >> 6;                  // 0..7
    const int lane = tid & 63;
    const int jb   = slot * UPB + wid * UPW;    // first of this wave's 4 units

    // Register-resident weight fragments: unit u, float4 m covers
    // k = m*256 + 4*lane .. +3  (identical fragment layout to v3 -> identical
    // numerics). 48 float4 = 192 VGPR; asm-pin so they can't be re-loaded.
    float4 wU[UPW][4], wR[UPW][4], wC[UPW][4];
#pragma unroll
    for (int u = 0; u < UPW; u++) {
        const float4* pu = (const float4*)(Wu + (size_t)(jb + u) * H);
        const float4* pr = (const float4*)(Wr + (size_t)(jb + u) * H);
        const float4* pw = (const float4*)(W  + (size_t)(jb + u) * H);
#pragma unroll
        for (int m = 0; m < 4; m++) {
            wU[u][m] = pu[m * 64 + lane];
            wR[u][m] = pr[m * 64 + lane];
            wC[u][m] = pw[m * 64 + lane];
        }
    }
#pragma unroll
    for (int u = 0; u < UPW; u++)
#pragma unroll
        for (int m = 0; m < 4; m++) {
            asm volatile("" : "+v"(wU[u][m].x), "+v"(wU[u][m].y), "+v"(wU[u][m].z), "+v"(wU[u][m].w));
            asm volatile("" : "+v"(wR[u][m].x), "+v"(wR[u][m].y), "+v"(wR[u][m].z), "+v"(wR[u][m].w));
            asm volatile("" : "+v"(wC[u][m].x), "+v"(wC[u][m].y), "+v"(wC[u][m].z), "+v"(wC[u][m].w));
        }

    float* outs = out + H;
    float hp[UPW] = {0.f, 0.f, 0.f, 0.f};       // previous h of our 4 units

    for (int t = 0; t < SEQ; t++) {
        float* hb = hs[t & 1];

        if (t == 0) {
            hb[wid * 128 + lane]      = 0.f;    // h0 = 0
            hb[wid * 128 + 64 + lane] = 0.f;
        } else {
            // wave w polls units [w*128, w*128+128) of slot (t&7) for tag t.
            const size_t base = (size_t)(t & (RING - 1)) * H + wid * 128 + lane;
            const unsigned long long* pL0 = thL + base;
            const unsigned long long* pL1 = pL0 + 64;
            const unsigned long long* pR0 = thR + base;
            const unsigned long long* pR1 = pR0 + 64;
            unsigned long long v0, v1;
            int tries = 0;
            for (;;) {
                unsigned long long a0, a1;
                asm volatile(
                    "global_load_dwordx2 %0, %2, off sc0\n\t"
                    "global_load_dwordx2 %1, %3, off sc0\n\t"
                    "s_waitcnt vmcnt(0)"
                    : "=&v"(a0), "=&v"(a1)
                    : "v"(pL0), "v"(pL1)
                    : "memory");
                const bool k0 = ((int)(a0 >> 32) == t);
                const bool k1 = ((int)(a1 >> 32) == t);
                if (__all(k0 & k1)) { v0 = a0; v1 = a1; break; }
                if (((++tries) & 7) == 0) {
                    // escalation: agent copy (always visible) — per-lane mix
                    unsigned long long b0 = __hip_atomic_load(pR0, __ATOMIC_RELAXED, __HIP_MEMORY_SCOPE_AGENT);
                    unsigned long long b1 = __hip_atomic_load(pR1, __ATOMIC_RELAXED, __HIP_MEMORY_SCOPE_AGENT);
                    const unsigned long long c0 = k0 ? a0 : b0;
                    const unsigned long long c1 = k1 ? a1 : b1;
                    if (__all(((int)(c0 >> 32) == t) & ((int)(c1 >> 32) == t))) {
                        v0 = c0; v1 = c1; break;
                    }
                }
            }
            hb[wid * 128 + lane]      = __uint_as_float((unsigned)v0);
            hb[wid * 128 + 64 + lane] = __uint_as_float((unsigned)v1);
        }
        __syncthreads();   // the ONLY barrier per step (hs double-buffered)

        // x-projections AFTER the barrier: ~900cy HBM miss hides under FMA.
        const float4 axu = *(const float4*)&xu[(size_t)t * H + jb];
        const float4 axr = *(const float4*)&xr[(size_t)t * H + jb];
        const float4 axc = *(const float4*)&xc[(size_t)t * H + jb];

        const float4* hsl = (const float4*)hb;
        float au[UPW] = {0.f, 0.f, 0.f, 0.f};
        float ar[UPW] = {0.f, 0.f, 0.f, 0.f};
        float aw[UPW] = {0.f, 0.f, 0.f, 0.f};
#pragma unroll
        for (int m = 0; m < 4; m++) {
            const float4 h = hsl[m * 64 + lane];
#pragma unroll
            for (int u = 0; u < UPW; u++) {
                au[u] += wU[u][m].x * h.x + wU[u][m].y * h.y + wU[u][m].z * h.z + wU[u][m].w * h.w;
                ar[u] += wR[u][m].x * h.x + wR[u][m].y * h.y + wR[u][m].z * h.z + wR[u][m].w * h.w;
                aw[u] += wC[u][m].x * h.x + wC[u][m].y * h.y + wC[u][m].z * h.z + wC[u][m].w * h.w;
            }
        }

#pragma unroll
        for (int off = 32; off > 0; off >>= 1)
#pragma unroll
            for (int u = 0; u < UPW; u++) {
                au[u] += __shfl_xor(au[u], off, 64);
                ar[u] += __shfl_xor(ar[u], off, 64);
                aw[u] += __shfl_xor(aw[u], off, 64);
            }

        // gates: all lanes compute (same wave-issue cost as lane0-only),
        // static unroll keeps everything in registers (no scratch).
        const float axuA[4] = {axu.x, axu.y, axu.z, axu.w};
        const float axrA[4] = {axr.x, axr.y, axr.z, axr.w};
        const float axcA[4] = {axc.x, axc.y, axc.z, axc.w};
        float hn[UPW];
#pragma unroll
        for (int u = 0; u < UPW; u++) {
            hn[u] = gatef(axuA[u], axrA[u], axcA[u], au[u], ar[u], aw[u], hp[u]);
            hp[u] = hn[u];
        }

        if (lane == 0) {
            const size_t q = (size_t)((t + 1) & (RING - 1)) * H + jb;
#pragma unroll
            for (int u = 0; u < UPW; u++) {
                const unsigned long long pkt =
                    ((unsigned long long)(unsigned)(t + 1) << 32) |
                    (unsigned long long)__float_as_uint(hn[u]);
                // local copy: plain store -> lands in XCD0's shared L2
                __hip_atomic_store(thL + q + u, pkt, __ATOMIC_RELAXED, __HIP_MEMORY_SCOPE_WORKGROUP);
                // shadow copy: agent scope -> MALL, for the fallback path
                __hip_atomic_store(thR + q + u, pkt, __ATOMIC_RELAXED, __HIP_MEMORY_SCOPE_AGENT);
            }
            *(float4*)&outs[(size_t)t * H + jb] = make_float4(hn[0], hn[1], hn[2], hn[3]);
            if (t == SEQ - 1)
                *(float4*)&out[jb] = make_float4(hn[0], hn[1], hn[2], hn[3]);
        }
        // no trailing barrier: next step writes the other hs buffer.
    }
}

// ---------------------------------------------------------------------------
extern "C" void kernel_launch(void* const* d_in, const int* in_sizes, int n_in,
                              void* d_out, int out_size, void* d_ws, size_t ws_size,
                              hipStream_t stream) {
    const float* x  = (const float*)d_in[0];
    const float* Uu = (const float*)d_in[1];
    const float* Wu = (const float*)d_in[2];
    const float* Bu = (const float*)d_in[3];
    const float* Ur = (const float*)d_in[4];
    const float* Wr = (const float*)d_in[5];
    const float* Br = (const float*)d_in[6];
    const float* U  = (const float*)d_in[7];
    const float* W  = (const float*)d_in[8];
    const float* B  = (const float*)d_in[9];

    char* ws = (char*)d_ws;
    const size_t MAT  = (size_t)SEQ * H * sizeof(float);          // 32 MB
    const size_t RB   = (size_t)RING * H * sizeof(unsigned long long); // 64 KB
    float* xu = (float*)(ws);
    float* xr = (float*)(ws + MAT);
    float* xc = (float*)(ws + 2 * MAT);
    unsigned long long* thL = (unsigned long long*)(ws + 3 * MAT);
    unsigned long long* thR = (unsigned long long*)(ws + 3 * MAT + RB);
    int* claim = (int*)(ws + 3 * MAT + 2 * RB);

    zero_claim<<<1, 64, 0, stream>>>(claim);

    dim3 g(H / 64, SEQ / 64, 3);
    proj_gemm<<<g, 256, 0, stream>>>(x, Uu, Bu, xu, Ur, Br, xr, U, B, xc);

    gru_scan<<<768, 512, 0, stream>>>(xu, xr, xc, Wu, Wr, W, thL, thR, claim,
                                      (float*)d_out);
}

// Round 7
// 14276.740 us; speedup vs baseline: 2.8175x; 2.8175x over previous
//
#include <hip/hip_runtime.h>

#define SEQ 8192
#define H 1024

// ---------------------------------------------------------------------------
// Projection GEMM (NT): C[i][j] = bias[j] + sum_k A[i][k]*B[j][k]
// (unchanged — ~0.6 ms, not the bottleneck)
// ---------------------------------------------------------------------------
#define KC 32
#define LDT 68

__global__ __launch_bounds__(256) void proj_gemm(
    const float* __restrict__ A,
    const float* __restrict__ B0, const float* __restrict__ b0, float* __restrict__ C0,
    const float* __restrict__ B1, const float* __restrict__ b1, float* __restrict__ C1,
    const float* __restrict__ B2, const float* __restrict__ b2, float* __restrict__ C2)
{
    __shared__ __align__(16) float As[KC * LDT];
    __shared__ __align__(16) float Bs[KC * LDT];

    const float* Bm; const float* bias; float* C;
    if (blockIdx.z == 0)      { Bm = B0; bias = b0; C = C0; }
    else if (blockIdx.z == 1) { Bm = B1; bias = b1; C = C1; }
    else                      { Bm = B2; bias = b2; C = C2; }

    const int j0 = blockIdx.x * 64;
    const int i0 = blockIdx.y * 64;
    const int tid = threadIdx.x;
    const int tx = tid & 15, ty = tid >> 4;
    const int lrow = tid >> 3;
    const int lkq  = tid & 7;

    float acc[4][4];
#pragma unroll
    for (int r = 0; r < 4; r++)
#pragma unroll
        for (int c = 0; c < 4; c++) acc[r][c] = 0.f;

    for (int k0 = 0; k0 < H; k0 += KC) {
#pragma unroll
        for (int half = 0; half < 2; half++) {
            const int row = lrow + half * 32;
            float4 a = *(const float4*)&A[(size_t)(i0 + row) * H + k0 + 4 * lkq];
            As[(4 * lkq + 0) * LDT + row] = a.x;
            As[(4 * lkq + 1) * LDT + row] = a.y;
            As[(4 * lkq + 2) * LDT + row] = a.z;
            As[(4 * lkq + 3) * LDT + row] = a.w;
            float4 b = *(const float4*)&Bm[(size_t)(j0 + row) * H + k0 + 4 * lkq];
            Bs[(4 * lkq + 0) * LDT + row] = b.x;
            Bs[(4 * lkq + 1) * LDT + row] = b.y;
            Bs[(4 * lkq + 2) * LDT + row] = b.z;
            Bs[(4 * lkq + 3) * LDT + row] = b.w;
        }
        __syncthreads();
#pragma unroll
        for (int k = 0; k < KC; k++) {
            float4 a4 = *(const float4*)&As[k * LDT + ty * 4];
            float4 b4 = *(const float4*)&Bs[k * LDT + tx * 4];
            acc[0][0] += a4.x * b4.x; acc[0][1] += a4.x * b4.y;
            acc[0][2] += a4.x * b4.z; acc[0][3] += a4.x * b4.w;
            acc[1][0] += a4.y * b4.x; acc[1][1] += a4.y * b4.y;
            acc[1][2] += a4.y * b4.z; acc[1][3] += a4.y * b4.w;
            acc[2][0] += a4.z * b4.x; acc[2][1] += a4.z * b4.y;
            acc[2][2] += a4.z * b4.z; acc[2][3] += a4.z * b4.w;
            acc[3][0] += a4.w * b4.x; acc[3][1] += a4.w * b4.y;
            acc[3][2] += a4.w * b4.z; acc[3][3] += a4.w * b4.w;
        }
        __syncthreads();
    }

    float4 bi = *(const float4*)&bias[j0 + tx * 4];
#pragma unroll
    for (int r = 0; r < 4; r++) {
        float4 o;
        o.x = acc[r][0] + bi.x; o.y = acc[r][1] + bi.y;
        o.z = acc[r][2] + bi.z; o.w = acc[r][3] + bi.w;
        *(float4*)&C[(size_t)(i0 + ty * 4 + r) * H + j0 + tx * 4] = o;
    }
}

// ---------------------------------------------------------------------------
// GRU scan v6: weights in LDS. v5 post-mortem proved (VGPR_Count=128 < 192
// needed) that weights are RE-READ EVERY STEP; v3's hidden cost was that
// stream hitting L2 at ~56 B/cy/CU (~3500 cy of the 5700 cy step).
//   - 128 blocks x 512 threads (8 waves); wave w owns unit j = bid*8 + w.
//     Per-unit math (fragment layout, FMA and shuffle-reduce order) is
//     IDENTICAL to v3 -> bit-identical results.
//   - All 3 weight matrices for the block's 8 units staged ONCE into 96 KB
//     LDS; per-step weight stream is 96 KB/CU from LDS at 256 B/cy (~384 cy
//     vs ~3500). Weight ds_reads are issued BEFORE the poll (lgkmcnt is
//     independent of the poll's vmcnt) so their latency hides under the
//     MALL round trip.
//   - Communication: v3's PROVEN tagged-ring protocol, unchanged: 8B
//     (value, tag) packets, system-scope relaxed atomics, ring of 8 slots,
//     no init (monotone tags; 0xAA poison never matches; dispatch-order
//     agnostic; producer of t+1 transitively proves all blocks consumed
//     slot t-7 -> WAR-safe).
//   - hs double-buffered -> ONE barrier per step: a wave can only overwrite
//     hs[t&1] at step t+2, after passing barrier t+1, which requires every
//     wave to have finished its step-t reads -> WAR-safe.
//   - x-projections prefetched by lane 0 before the poll (latency hides
//     under the first poll round trip).
// ---------------------------------------------------------------------------
#define RING 8
#define UPB  8                 // units per block
#define NBLK (H / UPB)         // 128 blocks

__global__ __launch_bounds__(512, 2) void gru_scan(
    const float* __restrict__ xu, const float* __restrict__ xr, const float* __restrict__ xc,
    const float* __restrict__ Wu, const float* __restrict__ Wr, const float* __restrict__ W,
    unsigned long long* __restrict__ th,  // RING*H tagged pairs (no init needed)
    float* __restrict__ out)              // d_out: [H h_final][SEQ*H outputs]
{
    // 96 KB weights + 8 KB hs = 104 KB LDS -> 1 block/CU
    __shared__ __align__(16) float4 wl[3 * UPB * 256];  // [mat][unit][k/4]
    __shared__ __align__(16) float hs[2][H];

    const int bid  = blockIdx.x;     // 0..127
    const int tid  = threadIdx.x;    // 0..511
    const int wid  = tid >> 6;       // 0..7
    const int lane = tid & 63;
    const int j    = bid * UPB + wid;     // hidden unit owned by this wave

    // ---- one-time: stage this block's weight rows into LDS --------------
    // wl index (M*UPB + u)*256 + c  <->  Wmat[(bid*UPB + u)*256 + c] (float4)
    {
        const float4* src[3] = {
            (const float4*)(Wu + (size_t)bid * UPB * H),
            (const float4*)(Wr + (size_t)bid * UPB * H),
            (const float4*)(W  + (size_t)bid * UPB * H)};
        for (int idx = tid; idx < 3 * UPB * 256; idx += 512) {
            const int M = idx >> 11;          // /2048
            wl[idx] = src[M][idx & 2047];     // rows are contiguous per mat
        }
    }
    __syncthreads();

    float* outs = out + H;
    float hprev = 0.f;               // lane0: previous h[j]

    const float4* wu4 = &wl[(0 * UPB + wid) * 256];
    const float4* wr4 = &wl[(1 * UPB + wid) * 256];
    const float4* wc4 = &wl[(2 * UPB + wid) * 256];

    for (int t = 0; t < SEQ; t++) {
        // prefetch x-projections (latency hides under the poll)
        float axu = 0.f, axr = 0.f, axc = 0.f;
        if (lane == 0) {
            axu = xu[(size_t)t * H + j];
            axr = xr[(size_t)t * H + j];
            axc = xc[(size_t)t * H + j];
        }

        // issue weight ds_reads early: lgkmcnt is independent of the poll's
        // vmcnt, so these complete during the MALL round trip.
        float4 wu[4], wr[4], wc[4];
#pragma unroll
        for (int m = 0; m < 4; m++) {
            wu[m] = wu4[m * 64 + lane];
            wr[m] = wr4[m * 64 + lane];
            wc[m] = wc4[m * 64 + lane];
        }

        float* hb = hs[t & 1];
        if (t == 0) {
            hb[wid * 128 + lane]      = 0.f;   // h0 = 0, nothing to poll
            hb[wid * 128 + 64 + lane] = 0.f;
        } else {
            // wave w polls units [w*128, w*128+128) of slot (t&7) for tag t
            const unsigned long long* p0 = th + (size_t)(t & (RING - 1)) * H
                                              + wid * 128 + lane;
            const unsigned long long* p1 = p0 + 64;
            unsigned long long v0, v1;
            for (;;) {
                v0 = __hip_atomic_load(p0, __ATOMIC_RELAXED, __HIP_MEMORY_SCOPE_SYSTEM);
                v1 = __hip_atomic_load(p1, __ATOMIC_RELAXED, __HIP_MEMORY_SCOPE_SYSTEM);
                if (__all(((int)(v0 >> 32) == t) & ((int)(v1 >> 32) == t))) break;
            }
            hb[wid * 128 + lane]      = __uint_as_float((unsigned)v0);
            hb[wid * 128 + 64 + lane] = __uint_as_float((unsigned)v1);
        }
        __syncthreads();   // the ONLY barrier per step (hs double-buffered)

        const float4* hsl = (const float4*)hb;
        float au = 0.f, ar = 0.f, aw = 0.f;
#pragma unroll
        for (int m = 0; m < 4; m++) {
            float4 h = hsl[m * 64 + lane];
            au += wu[m].x * h.x + wu[m].y * h.y + wu[m].z * h.z + wu[m].w * h.w;
            ar += wr[m].x * h.x + wr[m].y * h.y + wr[m].z * h.z + wr[m].w * h.w;
            aw += wc[m].x * h.x + wc[m].y * h.y + wc[m].z * h.z + wc[m].w * h.w;
        }

#pragma unroll
        for (int off = 32; off > 0; off >>= 1) {
            au += __shfl_xor(au, off, 64);
            ar += __shfl_xor(ar, off, 64);
            aw += __shfl_xor(aw, off, 64);
        }

        if (lane == 0) {
            float u    = 1.f / (1.f + __expf(-(axu + au)));
            float r    = 1.f / (1.f + __expf(-(axr + ar)));
            float cand = 1.f / (1.f + __expf(-(axc + r * aw)));
            float hnew = u * hprev + (1.f - u) * cand;
            hprev = hnew;
            // publish (value, tag=t+1) in ONE 8B system-scope store
            unsigned long long pkt =
                ((unsigned long long)(unsigned)(t + 1) << 32) |
                (unsigned long long)__float_as_uint(hnew);
            unsigned long long* q = th + (size_t)((t + 1) & (RING - 1)) * H + j;
            __hip_atomic_store(q, pkt, __ATOMIC_RELAXED, __HIP_MEMORY_SCOPE_SYSTEM);
            outs[(size_t)t * H + j] = hnew;       // plain cached store
            if (t == SEQ - 1) out[j] = hnew;      // h_final
        }
        // no trailing barrier: next step stages into the other hs buffer;
        // buffer reuse is gated by the NEXT step's barrier.
    }
}

// ---------------------------------------------------------------------------
extern "C" void kernel_launch(void* const* d_in, const int* in_sizes, int n_in,
                              void* d_out, int out_size, void* d_ws, size_t ws_size,
                              hipStream_t stream) {
    const float* x  = (const float*)d_in[0];
    const float* Uu = (const float*)d_in[1];
    const float* Wu = (const float*)d_in[2];
    const float* Bu = (const float*)d_in[3];
    const float* Ur = (const float*)d_in[4];
    const float* Wr = (const float*)d_in[5];
    const float* Br = (const float*)d_in[6];
    const float* U  = (const float*)d_in[7];
    const float* W  = (const float*)d_in[8];
    const float* B  = (const float*)d_in[9];

    char* ws = (char*)d_ws;
    const size_t MAT = (size_t)SEQ * H * sizeof(float);  // 32 MB
    float* xu = (float*)(ws);
    float* xr = (float*)(ws + MAT);
    float* xc = (float*)(ws + 2 * MAT);
    unsigned long long* th = (unsigned long long*)(ws + 3 * MAT);  // 64 KB ring

    dim3 g(H / 64, SEQ / 64, 3);
    proj_gemm<<<g, 256, 0, stream>>>(x, Uu, Bu, xu, Ur, Br, xr, U, B, xc);

    gru_scan<<<NBLK, 512, 0, stream>>>(xu, xr, xc, Wu, Wr, W, th, (float*)d_out);
}